// Round 3
// baseline (420.622 us; speedup 1.0000x reference)
//
#include <hip/hip_runtime.h>

// CommAttention: B=256, NB=16, HID=512, NH=8, KD=64.
// R3: BK=64 register-prefetch pipelined GEMMs, 512-thr blocks (8 waves,
// wave tile 64x32), unpadded LDS + b128 frags (m97 pattern), float4 B
// staging with in-register transpose, out_gemm split-K=8 + f32 atomics.

typedef short s16x4 __attribute__((ext_vector_type(4)));
typedef short s16x8 __attribute__((ext_vector_type(8)));
typedef float f32x4 __attribute__((ext_vector_type(4)));

__device__ __forceinline__ unsigned short f2bf(float f) {
  unsigned int u = __builtin_bit_cast(unsigned int, f);
  u += 0x7fffu + ((u >> 16) & 1u);   // round-to-nearest-even
  return (unsigned short)(u >> 16);
}
__device__ __forceinline__ float bf2f(unsigned short s) {
  unsigned int u = ((unsigned int)s) << 16;
  return __builtin_bit_cast(float, u);
}

// ---------------------------------------------------------------------------
// Prologue: h (2M fp32) -> bf16. grid 2048 x 256.
// ---------------------------------------------------------------------------
__global__ __launch_bounds__(256) void cvt_h(const float* __restrict__ h,
                                             unsigned short* __restrict__ hb)
{
  int i = (blockIdx.x * 256 + threadIdx.x) * 4;
  float4 v = *reinterpret_cast<const float4*>(h + i);
  s16x4 st = { (short)f2bf(v.x), (short)f2bf(v.y), (short)f2bf(v.z), (short)f2bf(v.w) };
  *reinterpret_cast<s16x4*>(hb + i) = st;
}

// ---------------------------------------------------------------------------
// Phase A: grouped QKV projection. Tile 128x128, BK=64, 512 thr (8 waves,
// wave tile 64x32). grid (80, 16): bx = m(2) x col(40) over [Q|K|V] concat.
// Register-prefetch pipeline: loads for step s+1 issue before MFMA of s.
// ---------------------------------------------------------------------------
__global__ __launch_bounds__(512) void qkv_gemm(
    const unsigned short* __restrict__ hb, const float* __restrict__ Wq,
    const float* __restrict__ Wk, const float* __restrict__ Wv,
    unsigned short* __restrict__ qo, unsigned short* __restrict__ ko,
    unsigned short* __restrict__ vo)
{
  const int g    = blockIdx.y;
  const int bx   = blockIdx.x;
  const int m0   = (bx / 40) * 128;
  const int n0   = (bx % 40) * 128;
  const int tid  = threadIdx.x;
  const int lane = tid & 63;
  const int wave = tid >> 6;            // 0..7
  const int wm   = (wave >> 2) * 64;
  const int wn   = (wave & 3) * 32;

  const float* W; unsigned short* out; size_t obase; int oldc, wN, c0;
  if (n0 < 512)       { W = Wq + (size_t)g * 262144;  out = qo; obase = (size_t)g * 512;  oldc = 8192;  wN = 512;  c0 = n0; }
  else if (n0 < 1024) { W = Wk + (size_t)g * 262144;  out = ko; obase = (size_t)g * 512;  oldc = 8192;  wN = 512;  c0 = n0 - 512; }
  else                { W = Wv + (size_t)g * 2097152; out = vo; obase = (size_t)g * 4096; oldc = 65536; wN = 4096; c0 = n0 - 1024; }

  const unsigned short* A = hb + (size_t)g * 512 + (size_t)m0 * 8192;

  __shared__ unsigned short As[128][64];
  __shared__ unsigned short Bs[128][64];

  f32x4 acc[4][2];
  #pragma unroll
  for (int i = 0; i < 4; i++)
    #pragma unroll
    for (int j = 0; j < 2; j++) acc[i][j] = (f32x4){0.f, 0.f, 0.f, 0.f};

  const int fr = lane & 15, fq = lane >> 4;
  const int bn  = (tid & 31) * 4;       // B col within tile
  const int bkr = tid >> 5;             // 0..15 -> k quad row

  s16x8 areg[2];
  f32x4 breg[4];

  // prefetch step 0
  #pragma unroll
  for (int p = 0; p < 2; p++) {
    int idx = p * 512 + tid, row = idx >> 3, kq = idx & 7;
    areg[p] = *reinterpret_cast<const s16x8*>(A + (size_t)row * 8192 + kq * 8);
  }
  #pragma unroll
  for (int l = 0; l < 4; l++)
    breg[l] = *reinterpret_cast<const f32x4*>(W + (size_t)(bkr * 4 + l) * wN + c0 + bn);

  for (int s = 0; s < 8; ++s) {
    const int k0 = s * 64;
    if (s) __syncthreads();
    // commit prefetched regs to LDS
    #pragma unroll
    for (int p = 0; p < 2; p++) {
      int idx = p * 512 + tid, row = idx >> 3, kq = idx & 7;
      *reinterpret_cast<s16x8*>(&As[row][kq * 8]) = areg[p];
    }
    #pragma unroll
    for (int j = 0; j < 4; j++) {
      s16x4 st = { (short)f2bf(breg[0][j]), (short)f2bf(breg[1][j]),
                   (short)f2bf(breg[2][j]), (short)f2bf(breg[3][j]) };
      *reinterpret_cast<s16x4*>(&Bs[bn + j][bkr * 4]) = st;
    }
    __syncthreads();
    // issue next step's global loads (overlap with MFMA below)
    if (s < 7) {
      const int kn = k0 + 64;
      #pragma unroll
      for (int p = 0; p < 2; p++) {
        int idx = p * 512 + tid, row = idx >> 3, kq = idx & 7;
        areg[p] = *reinterpret_cast<const s16x8*>(A + (size_t)row * 8192 + kn + kq * 8);
      }
      #pragma unroll
      for (int l = 0; l < 4; l++)
        breg[l] = *reinterpret_cast<const f32x4*>(W + (size_t)(kn + bkr * 4 + l) * wN + c0 + bn);
    }
    #pragma unroll
    for (int half = 0; half < 2; half++) {
      s16x8 af[4], bfr[2];
      #pragma unroll
      for (int mi = 0; mi < 4; mi++)
        af[mi] = *reinterpret_cast<const s16x8*>(&As[wm + mi * 16 + fr][half * 32 + fq * 8]);
      #pragma unroll
      for (int ni = 0; ni < 2; ni++)
        bfr[ni] = *reinterpret_cast<const s16x8*>(&Bs[wn + ni * 16 + fr][half * 32 + fq * 8]);
      #pragma unroll
      for (int mi = 0; mi < 4; mi++)
        #pragma unroll
        for (int ni = 0; ni < 2; ni++)
          acc[mi][ni] = __builtin_amdgcn_mfma_f32_16x16x32_bf16(af[mi], bfr[ni], acc[mi][ni], 0, 0, 0);
    }
  }

  #pragma unroll
  for (int mi = 0; mi < 4; mi++)
    #pragma unroll
    for (int ni = 0; ni < 2; ni++)
      #pragma unroll
      for (int r = 0; r < 4; r++) {
        int row = m0 + wm + mi * 16 + fq * 4 + r;
        int col = c0 + wn + ni * 16 + fr;
        out[obase + (size_t)row * oldc + col] = f2bf(acc[mi][ni][r]);
      }
}

// ---------------------------------------------------------------------------
// Phase B: per-(b,h) attention. grid 2048, block 256.
// ---------------------------------------------------------------------------
__global__ __launch_bounds__(256) void attn_kernel(
    const unsigned short* __restrict__ q, const unsigned short* __restrict__ k,
    const unsigned short* __restrict__ v, const int* __restrict__ mask,
    unsigned short* __restrict__ ctx)
{
  const int b  = blockIdx.x >> 3;
  const int hh = blockIdx.x & 7;
  const int tid = threadIdx.x;

  __shared__ float qs[16][65];
  __shared__ float ks[16][65];
  __shared__ float sc[16][16];

  {
    int n = tid >> 4, d4 = (tid & 15) * 4;
    size_t gi = ((size_t)(b * 16 + n) << 9) + (hh << 6) + d4;
    ushort4 qv = *reinterpret_cast<const ushort4*>(q + gi);
    ushort4 kv = *reinterpret_cast<const ushort4*>(k + gi);
    qs[n][d4] = bf2f(qv.x); qs[n][d4+1] = bf2f(qv.y); qs[n][d4+2] = bf2f(qv.z); qs[n][d4+3] = bf2f(qv.w);
    ks[n][d4] = bf2f(kv.x); ks[n][d4+1] = bf2f(kv.y); ks[n][d4+2] = bf2f(kv.z); ks[n][d4+3] = bf2f(kv.w);
  }
  __syncthreads();
  {
    int qi = tid >> 4, ki = tid & 15;
    float s = 0.f;
    #pragma unroll
    for (int j = 0; j < 64; j++) s += qs[qi][j] * ks[ki][j];
    sc[qi][ki] = s * 0.125f;
  }
  __syncthreads();
  if (tid < 16) {
    float m = sc[tid][0];
    #pragma unroll
    for (int j = 1; j < 16; j++) m = fmaxf(m, sc[tid][j]);
    float ev[16], sum = 0.f;
    #pragma unroll
    for (int j = 0; j < 16; j++) { ev[j] = __expf(sc[tid][j] - m); sum += ev[j]; }
    float scale = (mask[b * 16 + tid] != 0) ? (1.f / sum) : 0.f;
    #pragma unroll
    for (int j = 0; j < 16; j++) sc[tid][j] = ev[j] * scale;
  }
  __syncthreads();
  {
    int col4  = (tid & 127) * 4;
    int qbase = (tid >> 7) * 8;
    float a0[8], a1[8], a2[8], a3[8];
    #pragma unroll
    for (int j = 0; j < 8; j++) { a0[j] = 0.f; a1[j] = 0.f; a2[j] = 0.f; a3[j] = 0.f; }
    #pragma unroll
    for (int kk = 0; kk < 16; kk++) {
      ushort4 vv = *reinterpret_cast<const ushort4*>(
          v + ((size_t)(b * 16 + kk) << 12) + (hh << 9) + col4);
      float v0 = bf2f(vv.x), v1 = bf2f(vv.y), v2 = bf2f(vv.z), v3 = bf2f(vv.w);
      #pragma unroll
      for (int j = 0; j < 8; j++) {
        float p = sc[qbase + j][kk];
        a0[j] += p * v0; a1[j] += p * v1; a2[j] += p * v2; a3[j] += p * v3;
      }
    }
    #pragma unroll
    for (int j = 0; j < 8; j++) {
      ushort4 st = { f2bf(a0[j]), f2bf(a1[j]), f2bf(a2[j]), f2bf(a3[j]) };
      *reinterpret_cast<ushort4*>(
          ctx + ((size_t)(b * 16 + qbase + j) << 12) + (hh << 9) + col4) = st;
    }
  }
}

// ---------------------------------------------------------------------------
// Phase C: out += ctx @ Wo[g] (split-K=8, f32 atomics into zeroed d_out).
// Tile 128x128, BK=64, 512 thr. grid (64, 16): bx = sk(8) x m(2) x n(4).
// ---------------------------------------------------------------------------
__global__ __launch_bounds__(512) void out_gemm(
    const unsigned short* __restrict__ ctxp, const float* __restrict__ Wo,
    float* __restrict__ outp)
{
  const int g    = blockIdx.y;
  const int bx   = blockIdx.x;
  const int sk   = bx >> 3;             // 0..7
  const int m0   = ((bx >> 2) & 1) * 128;
  const int n0   = (bx & 3) * 128;
  const int tid  = threadIdx.x;
  const int lane = tid & 63;
  const int wave = tid >> 6;
  const int wm   = (wave >> 2) * 64;
  const int wn   = (wave & 3) * 32;

  const unsigned short* A = ctxp + (size_t)g * 4096 + (size_t)m0 * 65536;
  const float* W = Wo + (size_t)g * 2097152;

  __shared__ unsigned short As[128][64];
  __shared__ unsigned short Bs[128][64];

  f32x4 acc[4][2];
  #pragma unroll
  for (int i = 0; i < 4; i++)
    #pragma unroll
    for (int j = 0; j < 2; j++) acc[i][j] = (f32x4){0.f, 0.f, 0.f, 0.f};

  const int fr = lane & 15, fq = lane >> 4;
  const int bn  = (tid & 31) * 4;
  const int bkr = tid >> 5;
  const int kbase = sk * 512;

  s16x8 areg[2];
  f32x4 breg[4];

  #pragma unroll
  for (int p = 0; p < 2; p++) {
    int idx = p * 512 + tid, row = idx >> 3, kq = idx & 7;
    areg[p] = *reinterpret_cast<const s16x8*>(A + (size_t)row * 65536 + kbase + kq * 8);
  }
  #pragma unroll
  for (int l = 0; l < 4; l++)
    breg[l] = *reinterpret_cast<const f32x4*>(W + (size_t)(kbase + bkr * 4 + l) * 512 + n0 + bn);

  for (int s = 0; s < 8; ++s) {
    const int k0 = kbase + s * 64;
    if (s) __syncthreads();
    #pragma unroll
    for (int p = 0; p < 2; p++) {
      int idx = p * 512 + tid, row = idx >> 3, kq = idx & 7;
      *reinterpret_cast<s16x8*>(&As[row][kq * 8]) = areg[p];
    }
    #pragma unroll
    for (int j = 0; j < 4; j++) {
      s16x4 st = { (short)f2bf(breg[0][j]), (short)f2bf(breg[1][j]),
                   (short)f2bf(breg[2][j]), (short)f2bf(breg[3][j]) };
      *reinterpret_cast<s16x4*>(&Bs[bn + j][bkr * 4]) = st;
    }
    __syncthreads();
    if (s < 7) {
      const int kn = k0 + 64;
      #pragma unroll
      for (int p = 0; p < 2; p++) {
        int idx = p * 512 + tid, row = idx >> 3, kq = idx & 7;
        areg[p] = *reinterpret_cast<const s16x8*>(A + (size_t)row * 65536 + kn + kq * 8);
      }
      #pragma unroll
      for (int l = 0; l < 4; l++)
        breg[l] = *reinterpret_cast<const f32x4*>(W + (size_t)(kn + bkr * 4 + l) * 512 + n0 + bn);
    }
    #pragma unroll
    for (int half = 0; half < 2; half++) {
      s16x8 af[4], bfr[2];
      #pragma unroll
      for (int mi = 0; mi < 4; mi++)
        af[mi] = *reinterpret_cast<const s16x8*>(&As[wm + mi * 16 + fr][half * 32 + fq * 8]);
      #pragma unroll
      for (int ni = 0; ni < 2; ni++)
        bfr[ni] = *reinterpret_cast<const s16x8*>(&Bs[wn + ni * 16 + fr][half * 32 + fq * 8]);
      #pragma unroll
      for (int mi = 0; mi < 4; mi++)
        #pragma unroll
        for (int ni = 0; ni < 2; ni++)
          acc[mi][ni] = __builtin_amdgcn_mfma_f32_16x16x32_bf16(af[mi], bfr[ni], acc[mi][ni], 0, 0, 0);
    }
  }

  float* og = outp + (size_t)g * 512;
  #pragma unroll
  for (int mi = 0; mi < 4; mi++)
    #pragma unroll
    for (int ni = 0; ni < 2; ni++)
      #pragma unroll
      for (int r = 0; r < 4; r++) {
        int row = m0 + wm + mi * 16 + fq * 4 + r;
        int col = n0 + wn + ni * 16 + fr;
        atomicAdd(&og[(size_t)row * 8192 + col], acc[mi][ni][r]);
      }
}

// ---------------------------------------------------------------------------
extern "C" void kernel_launch(void* const* d_in, const int* in_sizes, int n_in,
                              void* d_out, int out_size, void* d_ws, size_t ws_size,
                              hipStream_t stream) {
  const float* h  = (const float*)d_in[0];
  const int* mask = (const int*)d_in[1];
  const float* Wk = (const float*)d_in[2];   // dict order: Wk before Wq
  const float* Wq = (const float*)d_in[3];
  const float* Wv = (const float*)d_in[4];
  const float* Wo = (const float*)d_in[5];
  float* out = (float*)d_out;

  // ws: q(4MB) | k(4MB) | v(33.5MB) | ctx(33.5MB); hb(4MB) aliases ctx start
  unsigned short* qws   = (unsigned short*)d_ws;
  unsigned short* kws   = qws + 2097152;
  unsigned short* vws   = kws + 2097152;
  unsigned short* ctxws = vws + 16777216;
  unsigned short* hb    = ctxws;   // dead before attn writes ctx

  cvt_h<<<2048, 256, 0, stream>>>(h, hb);
  hipMemsetAsync(d_out, 0, (size_t)out_size * sizeof(float), stream);
  qkv_gemm<<<dim3(80, 16), 512, 0, stream>>>(hb, Wq, Wk, Wv, qws, kws, vws);
  attn_kernel<<<2048, 256, 0, stream>>>(qws, kws, vws, mask, ctxws);
  out_gemm<<<dim3(64, 16), 512, 0, stream>>>(ctxws, Wo, out);
}